// Round 7
// baseline (285.436 us; speedup 1.0000x reference)
//
#include <hip/hip_runtime.h>
#include <math.h>

// Attend (talking-heads, causal) for B=4,H=16,N=1024,D=64 fp32.
// Round 7: r5 structure (CW=128, 2048 WGs/kernel) + cross-barrier load
// pipelining: raw lgkmcnt-only barriers (global loads stay in flight),
// register prefetch of K/V/bias one phase ahead. bf16 bias kept (r6).

#define NB 4
#define NH 16
#define NS 1024
#define ND 64
#define IT 16
#define JT 64
#define CW 128     // j-chunk width (8 chunks per row-tile)
#define HPAD 24    // dots [c=(i,j)][24] bf16: 48B rows, 16B-aligned

typedef __bf16 bf16x8 __attribute__((ext_vector_type(8)));
typedef __bf16 bf16x4 __attribute__((ext_vector_type(4)));
typedef float  f32x4  __attribute__((ext_vector_type(4)));

__device__ __forceinline__ f32x4 fzero4() {
  f32x4 z; z[0] = 0.f; z[1] = 0.f; z[2] = 0.f; z[3] = 0.f; return z;
}

// LDS-only barrier: do NOT drain vmcnt -> global prefetches survive.
__device__ __forceinline__ void lgkm_barrier() {
  asm volatile("s_waitcnt lgkmcnt(0)" ::: "memory");
  __builtin_amdgcn_s_barrier();
}

// heavy-first decode: r descending, chunk rotated per r (XCD spread).
__device__ __forceinline__ bool decode_chunk(int bid, int& b, int& i0, int& jlo,
                                             int& jhi, int& nsteps) {
  const int r = 63 - (bid >> 5);
  b = (bid >> 3) & 3;
  const int c = ((bid & 7) + r) & 7;
  i0 = r * IT;
  jlo = c * CW;
  if (jlo > i0 + IT - 1) return false;
  jhi = min(jlo + CW, i0 + IT);
  nsteps = (jhi - jlo + JT - 1) / JT;
  return true;
}

// ---------------- prep: Qb(1/8), Kb, VT [b,h,d,j], BiasB (bf16 triangle) ----------------
#define QK_BLKS   8192
#define VT_BLKS   1024
#define BIAS_BLKS 16384

__global__ __launch_bounds__(256)
void prep(const float* __restrict__ Q, const float* __restrict__ K,
          const float* __restrict__ V, const float* __restrict__ Bg,
          __bf16* __restrict__ Qb, __bf16* __restrict__ Kb,
          __bf16* __restrict__ VT, __bf16* __restrict__ BiasB) {
  __shared__ float tile[64][65];
  const int bid = blockIdx.x;
  const int t = threadIdx.x;
  if (bid < QK_BLKS) {
    const size_t nq4 = (size_t)NB * NH * NS * ND / 4;
    size_t idx = (size_t)bid * 256 + t;
    if (idx < nq4) {
      float4 x = reinterpret_cast<const float4*>(Q)[idx];
      bf16x4 o;
      o[0] = (__bf16)(x.x * 0.125f); o[1] = (__bf16)(x.y * 0.125f);
      o[2] = (__bf16)(x.z * 0.125f); o[3] = (__bf16)(x.w * 0.125f);
      reinterpret_cast<bf16x4*>(Qb)[idx] = o;
    } else {
      idx -= nq4;
      float4 x = reinterpret_cast<const float4*>(K)[idx];
      bf16x4 o;
      o[0] = (__bf16)x.x; o[1] = (__bf16)x.y; o[2] = (__bf16)x.z; o[3] = (__bf16)x.w;
      reinterpret_cast<bf16x4*>(Kb)[idx] = o;
    }
  } else if (bid < QK_BLKS + VT_BLKS) {
    const int vb = bid - QK_BLKS;
    const int bh = vb >> 4;
    const int j0 = (vb & 15) * 64;
    const float* vp = V + ((size_t)bh * NS + j0) * ND;
#pragma unroll
    for (int rep = 0; rep < 4; ++rep) {
      int lin = rep * 256 + t;
      int jj = lin >> 4;
      int dd = (lin & 15) * 4;
      float4 x = *reinterpret_cast<const float4*>(vp + (size_t)jj * ND + dd);
      tile[jj][dd] = x.x; tile[jj][dd + 1] = x.y;
      tile[jj][dd + 2] = x.z; tile[jj][dd + 3] = x.w;
    }
    __syncthreads();
    __bf16* op = VT + (size_t)bh * ND * NS + j0;
#pragma unroll
    for (int rep = 0; rep < 16; ++rep) {
      int lin = rep * 256 + t;
      int d = lin >> 6;
      int jj = lin & 63;
      op[(size_t)d * NS + jj] = (__bf16)tile[jj][d];
    }
  } else {
    size_t idx = (size_t)(bid - QK_BLKS - VT_BLKS) * 256 + t;   // float4 idx
    const int row = (int)(idx >> 8);
    const int i   = row & 1023;
    const int j4  = (int)(idx & 255);
    if (j4 * 4 <= i) {
      float4 x = reinterpret_cast<const float4*>(Bg)[idx];
      bf16x4 o;
      o[0] = (__bf16)x.x; o[1] = (__bf16)x.y; o[2] = (__bf16)x.z; o[3] = (__bf16)x.w;
      reinterpret_cast<bf16x4*>(BiasB)[idx] = o;
    }
  }
}

// ---------------- kernel 1: partial L ----------------
template <bool WS>
__global__ __launch_bounds__(512, 2)
void attend_l(const float* __restrict__ Qg, const float* __restrict__ Kg,
              const float* __restrict__ Bg, const float* __restrict__ Wpre,
              const __bf16* __restrict__ Qb, const __bf16* __restrict__ Kb,
              const __bf16* __restrict__ BiasB, float* __restrict__ Lws)
{
  int b, i0, jlo, jhi, nsteps;
  if (!decode_chunk(blockIdx.x, b, i0, jlo, jhi, nsteps)) return;

  const int tid = threadIdx.x;
  const int w = tid >> 6;
  const int lane = tid & 63;
  const int lr = lane & 15;
  const int lg = lane >> 4;

  __shared__ __align__(16) __bf16 dots[IT * JT * HPAD];  // 48KB

  bf16x8 wpreF;
#pragma unroll
  for (int e = 0; e < 8; ++e) wpreF[e] = (__bf16)0.f;
  if (lg < 2) {
#pragma unroll
    for (int e = 0; e < 8; ++e) wpreF[e] = (__bf16)Wpre[lr * NH + lg * 8 + e];
  }

  bf16x8 qF[2][2];
#pragma unroll
  for (int hh = 0; hh < 2; ++hh) {
    const int h = w + hh * 8;
    if constexpr (WS) {
      const __bf16* qp = Qb + ((size_t)(b * NH + h) * NS + i0 + lr) * ND + lg * 8;
      qF[hh][0] = *reinterpret_cast<const bf16x8*>(qp);
      qF[hh][1] = *reinterpret_cast<const bf16x8*>(qp + 32);
    } else {
      const float* qp = Qg + ((size_t)(b * NH + h) * NS + i0 + lr) * ND + lg * 8;
#pragma unroll
      for (int ks = 0; ks < 2; ++ks) {
        float4 x = *reinterpret_cast<const float4*>(qp + ks * 32);
        float4 y = *reinterpret_cast<const float4*>(qp + ks * 32 + 4);
        bf16x8 f;
        f[0] = (__bf16)(x.x * 0.125f); f[1] = (__bf16)(x.y * 0.125f);
        f[2] = (__bf16)(x.z * 0.125f); f[3] = (__bf16)(x.w * 0.125f);
        f[4] = (__bf16)(y.x * 0.125f); f[5] = (__bf16)(y.y * 0.125f);
        f[6] = (__bf16)(y.z * 0.125f); f[7] = (__bf16)(y.w * 0.125f);
        qF[hh][ks] = f;
      }
    }
  }

  // pipelined operand registers
  bf16x8 kreg[2][4][2];
  unsigned int braw[2][4][4];

  auto load_k = [&](int j0) {
#pragma unroll
    for (int hh = 0; hh < 2; ++hh) {
      const int h = w + hh * 8;
#pragma unroll
      for (int jb = 0; jb < 4; ++jb)
#pragma unroll
        for (int ks = 0; ks < 2; ++ks) {
          if constexpr (WS) {
            kreg[hh][jb][ks] = *reinterpret_cast<const bf16x8*>(
                Kb + ((size_t)(b * NH + h) * NS + j0 + jb * 16 + lr) * ND + ks * 32 + lg * 8);
          } else {
            const float* kp = Kg + ((size_t)(b * NH + h) * NS + j0 + jb * 16 + lr) * ND + ks * 32 + lg * 8;
            float4 x = *reinterpret_cast<const float4*>(kp);
            float4 y = *reinterpret_cast<const float4*>(kp + 4);
            bf16x8 f;
            f[0] = (__bf16)x.x; f[1] = (__bf16)x.y; f[2] = (__bf16)x.z; f[3] = (__bf16)x.w;
            f[4] = (__bf16)y.x; f[5] = (__bf16)y.y; f[6] = (__bf16)y.z; f[7] = (__bf16)y.w;
            kreg[hh][jb][ks] = f;
          }
        }
    }
  };
  auto load_bias = [&](int j0) {
#pragma unroll
    for (int ii = 0; ii < 2; ++ii) {
      const int gi = i0 + w + ii * 8;
#pragma unroll
      for (int qq = 0; qq < 4; ++qq)
#pragma unroll
        for (int rr = 0; rr < 4; ++rr) {
          const size_t idx = ((size_t)(lg * 4 + rr) * NS + gi) * NS + j0 + qq * 16 + lr;
          if constexpr (WS) braw[ii][qq][rr] = ((const unsigned short*)BiasB)[idx];
          else              braw[ii][qq][rr] = __float_as_uint(Bg[idx]);
        }
    }
  };
  auto bdec = [&](unsigned int u) -> float {
    if constexpr (WS) return __uint_as_float(u << 16);
    else              return __uint_as_float(u);
  };

  float Lp[2][4];
#pragma unroll
  for (int ii = 0; ii < 2; ++ii)
#pragma unroll
    for (int rr = 0; rr < 4; ++rr) Lp[ii][rr] = 0.f;

  load_k(jlo);
  load_bias(jlo);

  for (int s = 0; s < nsteps; ++s) {
    const int j0 = jlo + s * JT;
    const int jn = (j0 + JT < NS) ? (j0 + JT) : jlo;   // safe in-bounds prefetch

    if (s) lgkm_barrier();          // dots overwrite guard
    // ---- QK from kreg ----
#pragma unroll
    for (int hh = 0; hh < 2; ++hh) {
      const int h = w + hh * 8;
#pragma unroll
      for (int jb = 0; jb < 4; ++jb) {
        f32x4 acc = fzero4();
#pragma unroll
        for (int ks = 0; ks < 2; ++ks)
          acc = __builtin_amdgcn_mfma_f32_16x16x32_bf16(qF[hh][ks], kreg[hh][jb][ks], acc, 0, 0, 0);
#pragma unroll
        for (int rr = 0; rr < 4; ++rr)
          dots[((lg * 4 + rr) * JT + jb * 16 + lr) * HPAD + h] = (__bf16)acc[rr];
      }
    }
    load_k(jn);                     // in flight across barrier
    lgkm_barrier();
    // ---- mix + exp -> register L partials ----
#pragma unroll
    for (int ii = 0; ii < 2; ++ii) {
      const int i = w + ii * 8;
      const int gi = i0 + i;
#pragma unroll
      for (int qq = 0; qq < 4; ++qq) {
        bf16x8 bfr;
#pragma unroll
        for (int e = 0; e < 8; ++e) bfr[e] = (__bf16)0.f;
        if (lg < 2)
          bfr = *reinterpret_cast<const bf16x8*>(&dots[(i * JT + qq * 16 + lr) * HPAD + lg * 8]);
        f32x4 s1 = __builtin_amdgcn_mfma_f32_16x16x32_bf16(wpreF, bfr, fzero4(), 0, 0, 0);
        const int gj = j0 + qq * 16 + lr;
#pragma unroll
        for (int rr = 0; rr < 4; ++rr)
          if (gj <= gi) Lp[ii][rr] += __expf(s1[rr] + bdec(braw[ii][qq][rr]));
      }
    }
    load_bias(jn);                  // in flight across next barrier
  }

#pragma unroll
  for (int ii = 0; ii < 2; ++ii)
#pragma unroll
    for (int rr = 0; rr < 4; ++rr) {
      float v = Lp[ii][rr];
      v += __shfl_xor(v, 1, 64);
      v += __shfl_xor(v, 2, 64);
      v += __shfl_xor(v, 4, 64);
      v += __shfl_xor(v, 8, 64);
      if (lr == 0)
        atomicAdd(&Lws[(size_t)(b * NH + lg * 4 + rr) * NS + i0 + w + ii * 8], v);
    }
}

// ---------------- kernel 2: partial out ----------------
template <bool WS>
__global__ __launch_bounds__(512, 2)
void attend_o(const float* __restrict__ Qg, const float* __restrict__ Kg,
              const float* __restrict__ Vg, const float* __restrict__ Bg,
              const float* __restrict__ Wpre, const float* __restrict__ Wpost,
              const __bf16* __restrict__ Qb, const __bf16* __restrict__ Kb,
              const __bf16* __restrict__ VTb, const __bf16* __restrict__ BiasB,
              const float* __restrict__ Lws, float* __restrict__ Og)
{
  int b, i0, jlo, jhi, nsteps;
  if (!decode_chunk(blockIdx.x, b, i0, jlo, jhi, nsteps)) return;

  const int tid = threadIdx.x;
  const int w = tid >> 6;
  const int lane = tid & 63;
  const int lr = lane & 15;
  const int lg = lane >> 4;

  __shared__ __align__(16) __bf16 dots[IT * JT * HPAD];  // 48KB (dots, E' in place)
  __shared__ __align__(16) __bf16 sbP2[256 * 64];        // 32KB, 16B-unit XOR swizzle

  bf16x8 wpreF, wpostF;
#pragma unroll
  for (int e = 0; e < 8; ++e) { wpreF[e] = (__bf16)0.f; wpostF[e] = (__bf16)0.f; }
  if (lg < 2) {
#pragma unroll
    for (int e = 0; e < 8; ++e) {
      wpreF[e]  = (__bf16)Wpre [lr * NH + lg * 8 + e];
      wpostF[e] = (__bf16)Wpost[lr * NH + lg * 8 + e];
    }
  }

  bf16x8 qF[2][2];
#pragma unroll
  for (int hh = 0; hh < 2; ++hh) {
    const int h = w + hh * 8;
    if constexpr (WS) {
      const __bf16* qp = Qb + ((size_t)(b * NH + h) * NS + i0 + lr) * ND + lg * 8;
      qF[hh][0] = *reinterpret_cast<const bf16x8*>(qp);
      qF[hh][1] = *reinterpret_cast<const bf16x8*>(qp + 32);
    } else {
      const float* qp = Qg + ((size_t)(b * NH + h) * NS + i0 + lr) * ND + lg * 8;
#pragma unroll
      for (int ks = 0; ks < 2; ++ks) {
        float4 x = *reinterpret_cast<const float4*>(qp + ks * 32);
        float4 y = *reinterpret_cast<const float4*>(qp + ks * 32 + 4);
        bf16x8 f;
        f[0] = (__bf16)(x.x * 0.125f); f[1] = (__bf16)(x.y * 0.125f);
        f[2] = (__bf16)(x.z * 0.125f); f[3] = (__bf16)(x.w * 0.125f);
        f[4] = (__bf16)(y.x * 0.125f); f[5] = (__bf16)(y.y * 0.125f);
        f[6] = (__bf16)(y.z * 0.125f); f[7] = (__bf16)(y.w * 0.125f);
        qF[hh][ks] = f;
      }
    }
  }

  float linv[2][4];
#pragma unroll
  for (int ii = 0; ii < 2; ++ii)
#pragma unroll
    for (int rr = 0; rr < 4; ++rr)
      linv[ii][rr] = 1.f / Lws[(size_t)(b * NH + lg * 4 + rr) * NS + i0 + w + ii * 8];

  f32x4 oacc[2][4];
#pragma unroll
  for (int hh = 0; hh < 2; ++hh)
#pragma unroll
    for (int db = 0; db < 4; ++db) oacc[hh][db] = fzero4();

  // pipelined operand registers: K half-prefetch (hh=0), V full, bias raw
  bf16x8 kreg[4][2];
  bf16x8 vreg[2][4][2];
  unsigned int braw[2][4][4];

  auto load_k = [&](int j0) {
#pragma unroll
    for (int jb = 0; jb < 4; ++jb)
#pragma unroll
      for (int ks = 0; ks < 2; ++ks) {
        if constexpr (WS) {
          kreg[jb][ks] = *reinterpret_cast<const bf16x8*>(
              Kb + ((size_t)(b * NH + w) * NS + j0 + jb * 16 + lr) * ND + ks * 32 + lg * 8);
        } else {
          const float* kp = Kg + ((size_t)(b * NH + w) * NS + j0 + jb * 16 + lr) * ND + ks * 32 + lg * 8;
          float4 x = *reinterpret_cast<const float4*>(kp);
          float4 y = *reinterpret_cast<const float4*>(kp + 4);
          bf16x8 f;
          f[0] = (__bf16)x.x; f[1] = (__bf16)x.y; f[2] = (__bf16)x.z; f[3] = (__bf16)x.w;
          f[4] = (__bf16)y.x; f[5] = (__bf16)y.y; f[6] = (__bf16)y.z; f[7] = (__bf16)y.w;
          kreg[jb][ks] = f;
        }
      }
  };
  auto load_v = [&](int j0) {
#pragma unroll
    for (int hh = 0; hh < 2; ++hh) {
      const int g = w + hh * 8;
#pragma unroll
      for (int db = 0; db < 4; ++db) {
        if constexpr (WS) {
          const __bf16* vp = VTb + ((size_t)(b * NH + g) * ND + db * 16 + lr) * NS + j0 + lg * 8;
          vreg[hh][db][0] = *reinterpret_cast<const bf16x8*>(vp);
          vreg[hh][db][1] = *reinterpret_cast<const bf16x8*>(vp + 32);
        } else {
          const float* vb = Vg + (size_t)(b * NH + g) * NS * ND;
          bf16x8 f0, f1;
#pragma unroll
          for (int e = 0; e < 8; ++e) {
            f0[e] = (__bf16)vb[(size_t)(j0 + lg * 8 + e) * ND + db * 16 + lr];
            f1[e] = (__bf16)vb[(size_t)(j0 + 32 + lg * 8 + e) * ND + db * 16 + lr];
          }
          vreg[hh][db][0] = f0; vreg[hh][db][1] = f1;
        }
      }
    }
  };
  auto load_bias = [&](int j0) {
#pragma unroll
    for (int ii = 0; ii < 2; ++ii) {
      const int gi = i0 + w + ii * 8;
#pragma unroll
      for (int qq = 0; qq < 4; ++qq)
#pragma unroll
        for (int rr = 0; rr < 4; ++rr) {
          const size_t idx = ((size_t)(lg * 4 + rr) * NS + gi) * NS + j0 + qq * 16 + lr;
          if constexpr (WS) braw[ii][qq][rr] = ((const unsigned short*)BiasB)[idx];
          else              braw[ii][qq][rr] = __float_as_uint(Bg[idx]);
        }
    }
  };
  auto bdec = [&](unsigned int u) -> float {
    if constexpr (WS) return __uint_as_float(u << 16);
    else              return __uint_as_float(u);
  };

  auto pv_phase = [&]() {
#pragma unroll
    for (int hh = 0; hh < 2; ++hh) {
      const int g = w + hh * 8;
      const int row = g * IT + lr;
      const int sw = row & 7;
      bf16x8 pf0 = *reinterpret_cast<const bf16x8*>(&sbP2[row * 64 + ((lg ^ sw) << 3)]);
      bf16x8 pf1 = *reinterpret_cast<const bf16x8*>(&sbP2[row * 64 + (((4 + lg) ^ sw) << 3)]);
#pragma unroll
      for (int db = 0; db < 4; ++db) {
        oacc[hh][db] = __builtin_amdgcn_mfma_f32_16x16x32_bf16(pf0, vreg[hh][db][0], oacc[hh][db], 0, 0, 0);
        oacc[hh][db] = __builtin_amdgcn_mfma_f32_16x16x32_bf16(pf1, vreg[hh][db][1], oacc[hh][db], 0, 0, 0);
      }
    }
  };

  load_k(jlo);
  load_bias(jlo);

  for (int s = 0; s < nsteps; ++s) {
    const int j0 = jlo + s * JT;
    const int jn = (j0 + JT < NS) ? (j0 + JT) : jlo;

    // ---- phase1: PV(s-1) from vreg, QK(s): hh=0 from kreg, hh=1 inline ----
    if (s > 0) pv_phase();
#pragma unroll
    for (int jb = 0; jb < 4; ++jb) {
      f32x4 acc = fzero4();
#pragma unroll
      for (int ks = 0; ks < 2; ++ks)
        acc = __builtin_amdgcn_mfma_f32_16x16x32_bf16(qF[0][ks], kreg[jb][ks], acc, 0, 0, 0);
#pragma unroll
      for (int rr = 0; rr < 4; ++rr)
        dots[((lg * 4 + rr) * JT + jb * 16 + lr) * HPAD + w] = (__bf16)acc[rr];
    }
    {
      const int h = w + 8;
#pragma unroll
      for (int jb = 0; jb < 4; ++jb) {
        f32x4 acc = fzero4();
#pragma unroll
        for (int ks = 0; ks < 2; ++ks) {
          bf16x8 kf;
          if constexpr (WS) {
            kf = *reinterpret_cast<const bf16x8*>(
                Kb + ((size_t)(b * NH + h) * NS + j0 + jb * 16 + lr) * ND + ks * 32 + lg * 8);
          } else {
            const float* kp = Kg + ((size_t)(b * NH + h) * NS + j0 + jb * 16 + lr) * ND + ks * 32 + lg * 8;
            float4 x = *reinterpret_cast<const float4*>(kp);
            float4 y = *reinterpret_cast<const float4*>(kp + 4);
            kf[0] = (__bf16)x.x; kf[1] = (__bf16)x.y; kf[2] = (__bf16)x.z; kf[3] = (__bf16)x.w;
            kf[4] = (__bf16)y.x; kf[5] = (__bf16)y.y; kf[6] = (__bf16)y.z; kf[7] = (__bf16)y.w;
          }
          acc = __builtin_amdgcn_mfma_f32_16x16x32_bf16(qF[1][ks], kf, acc, 0, 0, 0);
        }
#pragma unroll
        for (int rr = 0; rr < 4; ++rr)
          dots[((lg * 4 + rr) * JT + jb * 16 + lr) * HPAD + h] = (__bf16)acc[rr];
      }
    }
    load_k(jn);        // K(s+1) in flight
    load_v(j0);        // V(s)  in flight (used next phase1 / epilogue)
    lgkm_barrier();

    // ---- phase2: mix1 (E' in place) + mix2 -> swizzled P2 ----
#pragma unroll
    for (int ii = 0; ii < 2; ++ii) {
      const int i = w + ii * 8;
      const int gi = i0 + i;
#pragma unroll
      for (int qq = 0; qq < 4; ++qq) {
        bf16x8 bfr;
#pragma unroll
        for (int e = 0; e < 8; ++e) bfr[e] = (__bf16)0.f;
        if (lg < 2)
          bfr = *reinterpret_cast<const bf16x8*>(&dots[(i * JT + qq * 16 + lr) * HPAD + lg * 8]);
        f32x4 s1 = __builtin_amdgcn_mfma_f32_16x16x32_bf16(wpreF, bfr, fzero4(), 0, 0, 0);
        const int gj = j0 + qq * 16 + lr;
        const int cc = i * JT + qq * 16 + lr;
#pragma unroll
        for (int rr = 0; rr < 4; ++rr) {
          float ev = 0.f;
          if (gj <= gi) ev = __expf(s1[rr] + bdec(braw[ii][qq][rr])) * linv[ii][rr];
          dots[cc * HPAD + lg * 4 + rr] = (__bf16)ev;
        }
      }
#pragma unroll
      for (int qq = 0; qq < 4; ++qq) {
        bf16x8 efr;
#pragma unroll
        for (int e = 0; e < 8; ++e) efr[e] = (__bf16)0.f;
        if (lg < 2)
          efr = *reinterpret_cast<const bf16x8*>(&dots[(i * JT + qq * 16 + lr) * HPAD + lg * 8]);
        f32x4 p2 = __builtin_amdgcn_mfma_f32_16x16x32_bf16(wpostF, efr, fzero4(), 0, 0, 0);
        const int u = (qq * 16 + lr) >> 3;
#pragma unroll
        for (int rr = 0; rr < 4; ++rr) {
          const int row = (lg * 4 + rr) * IT + i;
          sbP2[row * 64 + ((u ^ (i & 7)) << 3) + (lr & 7)] = (__bf16)p2[rr];
        }
      }
    }
    load_bias(jn);     // bias(s+1) in flight
    lgkm_barrier();
  }
  pv_phase();          // V(last)

#pragma unroll
  for (int hh = 0; hh < 2; ++hh) {
    const int g = w + hh * 8;
    float* ob = Og + ((size_t)(b * NH + g) * NS + i0) * ND;
#pragma unroll
    for (int db = 0; db < 4; ++db)
#pragma unroll
      for (int rr = 0; rr < 4; ++rr)
        atomicAdd(&ob[(size_t)(lg * 4 + rr) * ND + db * 16 + lr], oacc[hh][db][rr]);
  }
}

extern "C" void kernel_launch(void* const* d_in, const int* in_sizes, int n_in,
                              void* d_out, int out_size, void* d_ws, size_t ws_size,
                              hipStream_t stream) {
  const float* Q     = (const float*)d_in[0];
  const float* K     = (const float*)d_in[1];
  const float* V     = (const float*)d_in[2];
  const float* BIAS  = (const float*)d_in[3];
  const float* WPRE  = (const float*)d_in[4];
  const float* WPOST = (const float*)d_in[5];
  float* OUT = (float*)d_out;
  (void)in_sizes; (void)n_in;

  const size_t nelem  = (size_t)NB * NH * NS * ND;              // 4.19M
  const size_t nbias  = (size_t)NH * NS * NS;                   // 16.8M
  const size_t lbytes = (size_t)NB * NH * NS * sizeof(float);   // 256KB
  const size_t need   = lbytes + (3 * nelem + nbias) * sizeof(__bf16);  // ~59MB

  float* Lws = (float*)d_ws;
  hipMemsetAsync(d_ws, 0, lbytes, stream);
  hipMemsetAsync(d_out, 0, (size_t)out_size * sizeof(float), stream);

  if (ws_size >= need) {
    __bf16* Qb = (__bf16*)((char*)d_ws + lbytes);
    __bf16* Kb = Qb + nelem;
    __bf16* VT = Kb + nelem;
    __bf16* BB = VT + nelem;
    hipLaunchKernelGGL(prep, dim3(QK_BLKS + VT_BLKS + BIAS_BLKS), dim3(256), 0, stream,
                       Q, K, V, BIAS, Qb, Kb, VT, BB);
    hipLaunchKernelGGL((attend_l<true>), dim3(2048), dim3(512), 0, stream,
                       Q, K, BIAS, WPRE, Qb, Kb, BB, Lws);
    hipLaunchKernelGGL((attend_o<true>), dim3(2048), dim3(512), 0, stream,
                       Q, K, V, BIAS, WPRE, WPOST, Qb, Kb, VT, BB, Lws, OUT);
  } else {
    hipLaunchKernelGGL((attend_l<false>), dim3(2048), dim3(512), 0, stream,
                       Q, K, BIAS, WPRE, (const __bf16*)nullptr,
                       (const __bf16*)nullptr, (const __bf16*)nullptr, Lws);
    hipLaunchKernelGGL((attend_o<false>), dim3(2048), dim3(512), 0, stream,
                       Q, K, V, BIAS, WPRE, WPOST, (const __bf16*)nullptr,
                       (const __bf16*)nullptr, (const __bf16*)nullptr,
                       (const __bf16*)nullptr, Lws, OUT);
  }
}

// Round 8
// 258.705 us; speedup vs baseline: 1.1033x; 1.1033x over previous
//
#include <hip/hip_runtime.h>
#include <math.h>

// Attend (talking-heads, causal) for B=4,H=16,N=1024,D=64 fp32.
// Round 8: uniform single-step work items. Each WG = exactly one
// (b, i-tile16, j-chunk64) step; grid = exact triangular item count (2176
// per kernel), heavy rows first, no dead WGs, no multi-step loops.
// K prefetched at t=0 (dead after phase1); bias/L/V issued at phase2 start
// (live after) -> phase-disjoint register lifetimes, peak <= ~128 VGPR.
// lgkm-only barriers keep global loads in flight across barriers.

#define NB 4
#define NH 16
#define NS 1024
#define ND 64
#define IT 16
#define JT 64
#define NITEM 544   // per batch: sum_r (floor(r/4)+1)
#define HPAD 24     // dots [c=(i,j)][24] bf16: 48B rows, 16B-aligned

typedef __bf16 bf16x8 __attribute__((ext_vector_type(8)));
typedef __bf16 bf16x4 __attribute__((ext_vector_type(4)));
typedef float  f32x4  __attribute__((ext_vector_type(4)));

__device__ __forceinline__ f32x4 fzero4() {
  f32x4 z; z[0] = 0.f; z[1] = 0.f; z[2] = 0.f; z[3] = 0.f; return z;
}

// LDS-only barrier: global loads stay in flight.
__device__ __forceinline__ void lgkm_barrier() {
  asm volatile("s_waitcnt lgkmcnt(0)" ::: "memory");
  __builtin_amdgcn_s_barrier();
}

// item q in [0,544) -> (i0, j0). r = 4m+t has m+1 chunks; C(4m+t)=(m+1)(2m+t).
__device__ __forceinline__ void decode_item(int q, int& i0, int& j0) {
  int m = (int)sqrtf((float)q * 0.5f) + 1;
  while (2 * m * (m + 1) > q) --m;
  while (2 * (m + 1) * (m + 2) <= q) ++m;
  const int off = q - 2 * m * (m + 1);
  const int t = off / (m + 1);
  const int c = off - t * (m + 1);
  i0 = (4 * m + t) * IT;
  j0 = JT * c;
}

// ---------------- prep: Qb(1/8), Kb, VT [b,h,d,j], BiasB (bf16 triangle) ----------------
#define QK_BLKS   8192
#define VT_BLKS   1024
#define BIAS_BLKS 16384

__global__ __launch_bounds__(256)
void prep(const float* __restrict__ Q, const float* __restrict__ K,
          const float* __restrict__ V, const float* __restrict__ Bg,
          __bf16* __restrict__ Qb, __bf16* __restrict__ Kb,
          __bf16* __restrict__ VT, __bf16* __restrict__ BiasB) {
  __shared__ float tile[64][65];
  const int bid = blockIdx.x;
  const int t = threadIdx.x;
  if (bid < QK_BLKS) {
    const size_t nq4 = (size_t)NB * NH * NS * ND / 4;
    size_t idx = (size_t)bid * 256 + t;
    if (idx < nq4) {
      float4 x = reinterpret_cast<const float4*>(Q)[idx];
      bf16x4 o;
      o[0] = (__bf16)(x.x * 0.125f); o[1] = (__bf16)(x.y * 0.125f);
      o[2] = (__bf16)(x.z * 0.125f); o[3] = (__bf16)(x.w * 0.125f);
      reinterpret_cast<bf16x4*>(Qb)[idx] = o;
    } else {
      idx -= nq4;
      float4 x = reinterpret_cast<const float4*>(K)[idx];
      bf16x4 o;
      o[0] = (__bf16)x.x; o[1] = (__bf16)x.y; o[2] = (__bf16)x.z; o[3] = (__bf16)x.w;
      reinterpret_cast<bf16x4*>(Kb)[idx] = o;
    }
  } else if (bid < QK_BLKS + VT_BLKS) {
    const int vb = bid - QK_BLKS;
    const int bh = vb >> 4;
    const int j0 = (vb & 15) * 64;
    const float* vp = V + ((size_t)bh * NS + j0) * ND;
#pragma unroll
    for (int rep = 0; rep < 4; ++rep) {
      int lin = rep * 256 + t;
      int jj = lin >> 4;
      int dd = (lin & 15) * 4;
      float4 x = *reinterpret_cast<const float4*>(vp + (size_t)jj * ND + dd);
      tile[jj][dd] = x.x; tile[jj][dd + 1] = x.y;
      tile[jj][dd + 2] = x.z; tile[jj][dd + 3] = x.w;
    }
    __syncthreads();
    __bf16* op = VT + (size_t)bh * ND * NS + j0;
#pragma unroll
    for (int rep = 0; rep < 16; ++rep) {
      int lin = rep * 256 + t;
      int d = lin >> 6;
      int jj = lin & 63;
      op[(size_t)d * NS + jj] = (__bf16)tile[jj][d];
    }
  } else {
    size_t idx = (size_t)(bid - QK_BLKS - VT_BLKS) * 256 + t;   // float4 idx
    const int row = (int)(idx >> 8);
    const int i   = row & 1023;
    const int j4  = (int)(idx & 255);
    if (j4 * 4 <= i) {
      float4 x = reinterpret_cast<const float4*>(Bg)[idx];
      bf16x4 o;
      o[0] = (__bf16)x.x; o[1] = (__bf16)x.y; o[2] = (__bf16)x.z; o[3] = (__bf16)x.w;
      reinterpret_cast<bf16x4*>(BiasB)[idx] = o;
    }
  }
}

// ---------------- kernel 1: partial L (one step per WG) ----------------
template <bool WS>
__global__ __launch_bounds__(512, 4)
void attend_l(const float* __restrict__ Qg, const float* __restrict__ Kg,
              const float* __restrict__ Bg, const float* __restrict__ Wpre,
              const __bf16* __restrict__ Qb, const __bf16* __restrict__ Kb,
              const __bf16* __restrict__ BiasB, float* __restrict__ Lws)
{
  const int bid = blockIdx.x;
  const int b = bid / NITEM;
  int i0, j0;
  decode_item(NITEM - 1 - (bid - b * NITEM), i0, j0);   // heavy rows first

  const int tid = threadIdx.x;
  const int w = tid >> 6;
  const int lane = tid & 63;
  const int lr = lane & 15;
  const int lg = lane >> 4;

  __shared__ __align__(16) __bf16 dots[IT * JT * HPAD];  // 48KB

  // prologue: K (dead after phase1), Q, wpre
  bf16x8 kreg[2][4][2];
#pragma unroll
  for (int hh = 0; hh < 2; ++hh) {
    const int h = w + hh * 8;
#pragma unroll
    for (int jb = 0; jb < 4; ++jb)
#pragma unroll
      for (int ks = 0; ks < 2; ++ks) {
        if constexpr (WS) {
          kreg[hh][jb][ks] = *reinterpret_cast<const bf16x8*>(
              Kb + ((size_t)(b * NH + h) * NS + j0 + jb * 16 + lr) * ND + ks * 32 + lg * 8);
        } else {
          const float* kp = Kg + ((size_t)(b * NH + h) * NS + j0 + jb * 16 + lr) * ND + ks * 32 + lg * 8;
          float4 x = *reinterpret_cast<const float4*>(kp);
          float4 y = *reinterpret_cast<const float4*>(kp + 4);
          bf16x8 f;
          f[0] = (__bf16)x.x; f[1] = (__bf16)x.y; f[2] = (__bf16)x.z; f[3] = (__bf16)x.w;
          f[4] = (__bf16)y.x; f[5] = (__bf16)y.y; f[6] = (__bf16)y.z; f[7] = (__bf16)y.w;
          kreg[hh][jb][ks] = f;
        }
      }
  }
  bf16x8 qF[2][2];
#pragma unroll
  for (int hh = 0; hh < 2; ++hh) {
    const int h = w + hh * 8;
    if constexpr (WS) {
      const __bf16* qp = Qb + ((size_t)(b * NH + h) * NS + i0 + lr) * ND + lg * 8;
      qF[hh][0] = *reinterpret_cast<const bf16x8*>(qp);
      qF[hh][1] = *reinterpret_cast<const bf16x8*>(qp + 32);
    } else {
      const float* qp = Qg + ((size_t)(b * NH + h) * NS + i0 + lr) * ND + lg * 8;
#pragma unroll
      for (int ks = 0; ks < 2; ++ks) {
        float4 x = *reinterpret_cast<const float4*>(qp + ks * 32);
        float4 y = *reinterpret_cast<const float4*>(qp + ks * 32 + 4);
        bf16x8 f;
        f[0] = (__bf16)(x.x * 0.125f); f[1] = (__bf16)(x.y * 0.125f);
        f[2] = (__bf16)(x.z * 0.125f); f[3] = (__bf16)(x.w * 0.125f);
        f[4] = (__bf16)(y.x * 0.125f); f[5] = (__bf16)(y.y * 0.125f);
        f[6] = (__bf16)(y.z * 0.125f); f[7] = (__bf16)(y.w * 0.125f);
        qF[hh][ks] = f;
      }
    }
  }
  bf16x8 wpreF;
#pragma unroll
  for (int e = 0; e < 8; ++e) wpreF[e] = (__bf16)0.f;
  if (lg < 2) {
#pragma unroll
    for (int e = 0; e < 8; ++e) wpreF[e] = (__bf16)Wpre[lr * NH + lg * 8 + e];
  }

  // ---- phase1: QK -> dots ----
#pragma unroll
  for (int hh = 0; hh < 2; ++hh) {
    const int h = w + hh * 8;
#pragma unroll
    for (int jb = 0; jb < 4; ++jb) {
      f32x4 acc = fzero4();
#pragma unroll
      for (int ks = 0; ks < 2; ++ks)
        acc = __builtin_amdgcn_mfma_f32_16x16x32_bf16(qF[hh][ks], kreg[hh][jb][ks], acc, 0, 0, 0);
#pragma unroll
      for (int rr = 0; rr < 4; ++rr)
        dots[((lg * 4 + rr) * JT + jb * 16 + lr) * HPAD + h] = (__bf16)acc[rr];
    }
  }
  lgkm_barrier();

  // ---- phase2: bias loads, mix + exp -> L partials ----
  float br[2][4][4];
#pragma unroll
  for (int ii = 0; ii < 2; ++ii) {
    const int gi = i0 + w + ii * 8;
#pragma unroll
    for (int qq = 0; qq < 4; ++qq)
#pragma unroll
      for (int rr = 0; rr < 4; ++rr) {
        const size_t idx = ((size_t)(lg * 4 + rr) * NS + gi) * NS + j0 + qq * 16 + lr;
        if constexpr (WS) br[ii][qq][rr] = (float)BiasB[idx];
        else              br[ii][qq][rr] = Bg[idx];
      }
  }
  float Lp[2][4];
#pragma unroll
  for (int ii = 0; ii < 2; ++ii)
#pragma unroll
    for (int rr = 0; rr < 4; ++rr) Lp[ii][rr] = 0.f;

#pragma unroll
  for (int ii = 0; ii < 2; ++ii) {
    const int i = w + ii * 8;
    const int gi = i0 + i;
#pragma unroll
    for (int qq = 0; qq < 4; ++qq) {
      bf16x8 bfr;
#pragma unroll
      for (int e = 0; e < 8; ++e) bfr[e] = (__bf16)0.f;
      if (lg < 2)
        bfr = *reinterpret_cast<const bf16x8*>(&dots[(i * JT + qq * 16 + lr) * HPAD + lg * 8]);
      f32x4 s1 = __builtin_amdgcn_mfma_f32_16x16x32_bf16(wpreF, bfr, fzero4(), 0, 0, 0);
      const int gj = j0 + qq * 16 + lr;
#pragma unroll
      for (int rr = 0; rr < 4; ++rr)
        if (gj <= gi) Lp[ii][rr] += __expf(s1[rr] + br[ii][qq][rr]);
    }
  }

#pragma unroll
  for (int ii = 0; ii < 2; ++ii)
#pragma unroll
    for (int rr = 0; rr < 4; ++rr) {
      float v = Lp[ii][rr];
      v += __shfl_xor(v, 1, 64);
      v += __shfl_xor(v, 2, 64);
      v += __shfl_xor(v, 4, 64);
      v += __shfl_xor(v, 8, 64);
      if (lr == 0)
        atomicAdd(&Lws[(size_t)(b * NH + lg * 4 + rr) * NS + i0 + w + ii * 8], v);
    }
}

// ---------------- kernel 2: partial out (one step per WG) ----------------
template <bool WS>
__global__ __launch_bounds__(512, 4)
void attend_o(const float* __restrict__ Qg, const float* __restrict__ Kg,
              const float* __restrict__ Vg, const float* __restrict__ Bg,
              const float* __restrict__ Wpre, const float* __restrict__ Wpost,
              const __bf16* __restrict__ Qb, const __bf16* __restrict__ Kb,
              const __bf16* __restrict__ VTb, const __bf16* __restrict__ BiasB,
              const float* __restrict__ Lws, float* __restrict__ Og)
{
  const int bid = blockIdx.x;
  const int b = bid / NITEM;
  int i0, j0;
  decode_item(NITEM - 1 - (bid - b * NITEM), i0, j0);

  const int tid = threadIdx.x;
  const int w = tid >> 6;
  const int lane = tid & 63;
  const int lr = lane & 15;
  const int lg = lane >> 4;

  __shared__ __align__(16) __bf16 dots[IT * JT * HPAD];  // 48KB (dots, E' in place)
  __shared__ __align__(16) __bf16 sbP2[256 * 64];        // 32KB, XOR-swizzled

  // prologue: K (dead after phase1), Q, w-matrices
  bf16x8 kreg[2][4][2];
#pragma unroll
  for (int hh = 0; hh < 2; ++hh) {
    const int h = w + hh * 8;
#pragma unroll
    for (int jb = 0; jb < 4; ++jb)
#pragma unroll
      for (int ks = 0; ks < 2; ++ks) {
        if constexpr (WS) {
          kreg[hh][jb][ks] = *reinterpret_cast<const bf16x8*>(
              Kb + ((size_t)(b * NH + h) * NS + j0 + jb * 16 + lr) * ND + ks * 32 + lg * 8);
        } else {
          const float* kp = Kg + ((size_t)(b * NH + h) * NS + j0 + jb * 16 + lr) * ND + ks * 32 + lg * 8;
          float4 x = *reinterpret_cast<const float4*>(kp);
          float4 y = *reinterpret_cast<const float4*>(kp + 4);
          bf16x8 f;
          f[0] = (__bf16)x.x; f[1] = (__bf16)x.y; f[2] = (__bf16)x.z; f[3] = (__bf16)x.w;
          f[4] = (__bf16)y.x; f[5] = (__bf16)y.y; f[6] = (__bf16)y.z; f[7] = (__bf16)y.w;
          kreg[hh][jb][ks] = f;
        }
      }
  }
  bf16x8 qF[2][2];
#pragma unroll
  for (int hh = 0; hh < 2; ++hh) {
    const int h = w + hh * 8;
    if constexpr (WS) {
      const __bf16* qp = Qb + ((size_t)(b * NH + h) * NS + i0 + lr) * ND + lg * 8;
      qF[hh][0] = *reinterpret_cast<const bf16x8*>(qp);
      qF[hh][1] = *reinterpret_cast<const bf16x8*>(qp + 32);
    } else {
      const float* qp = Qg + ((size_t)(b * NH + h) * NS + i0 + lr) * ND + lg * 8;
#pragma unroll
      for (int ks = 0; ks < 2; ++ks) {
        float4 x = *reinterpret_cast<const float4*>(qp + ks * 32);
        float4 y = *reinterpret_cast<const float4*>(qp + ks * 32 + 4);
        bf16x8 f;
        f[0] = (__bf16)(x.x * 0.125f); f[1] = (__bf16)(x.y * 0.125f);
        f[2] = (__bf16)(x.z * 0.125f); f[3] = (__bf16)(x.w * 0.125f);
        f[4] = (__bf16)(y.x * 0.125f); f[5] = (__bf16)(y.y * 0.125f);
        f[6] = (__bf16)(y.z * 0.125f); f[7] = (__bf16)(y.w * 0.125f);
        qF[hh][ks] = f;
      }
    }
  }
  bf16x8 wpreF, wpostF;
#pragma unroll
  for (int e = 0; e < 8; ++e) { wpreF[e] = (__bf16)0.f; wpostF[e] = (__bf16)0.f; }
  if (lg < 2) {
#pragma unroll
    for (int e = 0; e < 8; ++e) {
      wpreF[e]  = (__bf16)Wpre [lr * NH + lg * 8 + e];
      wpostF[e] = (__bf16)Wpost[lr * NH + lg * 8 + e];
    }
  }

  // ---- phase1: QK -> dots ----
#pragma unroll
  for (int hh = 0; hh < 2; ++hh) {
    const int h = w + hh * 8;
#pragma unroll
    for (int jb = 0; jb < 4; ++jb) {
      f32x4 acc = fzero4();
#pragma unroll
      for (int ks = 0; ks < 2; ++ks)
        acc = __builtin_amdgcn_mfma_f32_16x16x32_bf16(qF[hh][ks], kreg[hh][jb][ks], acc, 0, 0, 0);
#pragma unroll
      for (int rr = 0; rr < 4; ++rr)
        dots[((lg * 4 + rr) * JT + jb * 16 + lr) * HPAD + h] = (__bf16)acc[rr];
    }
  }
  lgkm_barrier();

  // ---- phase2: issue V(db0,1)/bias/L loads, then mix1+mix2 ----
  bf16x8 vA[2][2], vB[2][2];
  auto loadv = [&](bf16x8 (&buf)[2][2], int db) {
#pragma unroll
    for (int hh = 0; hh < 2; ++hh) {
      const int g = w + hh * 8;
      if constexpr (WS) {
        const __bf16* vp = VTb + ((size_t)(b * NH + g) * ND + db * 16 + lr) * NS + j0 + lg * 8;
        buf[hh][0] = *reinterpret_cast<const bf16x8*>(vp);
        buf[hh][1] = *reinterpret_cast<const bf16x8*>(vp + 32);
      } else {
        const float* vb = Vg + (size_t)(b * NH + g) * NS * ND;
        bf16x8 f0, f1;
#pragma unroll
        for (int e = 0; e < 8; ++e) {
          f0[e] = (__bf16)vb[(size_t)(j0 + lg * 8 + e) * ND + db * 16 + lr];
          f1[e] = (__bf16)vb[(size_t)(j0 + 32 + lg * 8 + e) * ND + db * 16 + lr];
        }
        buf[hh][0] = f0; buf[hh][1] = f1;
      }
    }
  };
  loadv(vA, 0);
  loadv(vB, 1);

  float br[2][4][4];
  float linv[2][4];
#pragma unroll
  for (int ii = 0; ii < 2; ++ii) {
    const int gi = i0 + w + ii * 8;
#pragma unroll
    for (int rr = 0; rr < 4; ++rr)
      linv[ii][rr] = 1.f / Lws[(size_t)(b * NH + lg * 4 + rr) * NS + gi];
#pragma unroll
    for (int qq = 0; qq < 4; ++qq)
#pragma unroll
      for (int rr = 0; rr < 4; ++rr) {
        const size_t idx = ((size_t)(lg * 4 + rr) * NS + gi) * NS + j0 + qq * 16 + lr;
        if constexpr (WS) br[ii][qq][rr] = (float)BiasB[idx];
        else              br[ii][qq][rr] = Bg[idx];
      }
  }

#pragma unroll
  for (int ii = 0; ii < 2; ++ii) {
    const int i = w + ii * 8;
    const int gi = i0 + i;
    // mix1: E' in place over dots (own rows)
#pragma unroll
    for (int qq = 0; qq < 4; ++qq) {
      bf16x8 bfr;
#pragma unroll
      for (int e = 0; e < 8; ++e) bfr[e] = (__bf16)0.f;
      if (lg < 2)
        bfr = *reinterpret_cast<const bf16x8*>(&dots[(i * JT + qq * 16 + lr) * HPAD + lg * 8]);
      f32x4 s1 = __builtin_amdgcn_mfma_f32_16x16x32_bf16(wpreF, bfr, fzero4(), 0, 0, 0);
      const int gj = j0 + qq * 16 + lr;
      const int cc = i * JT + qq * 16 + lr;
#pragma unroll
      for (int rr = 0; rr < 4; ++rr) {
        float ev = 0.f;
        if (gj <= gi) ev = __expf(s1[rr] + br[ii][qq][rr]) * linv[ii][rr];
        dots[cc * HPAD + lg * 4 + rr] = (__bf16)ev;
      }
    }
    // mix2: own rows -> swizzled P2
#pragma unroll
    for (int qq = 0; qq < 4; ++qq) {
      bf16x8 efr;
#pragma unroll
      for (int e = 0; e < 8; ++e) efr[e] = (__bf16)0.f;
      if (lg < 2)
        efr = *reinterpret_cast<const bf16x8*>(&dots[(i * JT + qq * 16 + lr) * HPAD + lg * 8]);
      f32x4 p2 = __builtin_amdgcn_mfma_f32_16x16x32_bf16(wpostF, efr, fzero4(), 0, 0, 0);
      const int u = (qq * 16 + lr) >> 3;
#pragma unroll
      for (int rr = 0; rr < 4; ++rr) {
        const int row = (lg * 4 + rr) * IT + i;
        sbP2[row * 64 + ((u ^ (i & 7)) << 3) + (lr & 7)] = (__bf16)p2[rr];
      }
    }
  }
  lgkm_barrier();

  // ---- PV: pf from sbP2, V streamed (vA/vB rolling) ----
  f32x4 oacc[2][4];
#pragma unroll
  for (int hh = 0; hh < 2; ++hh)
#pragma unroll
    for (int db = 0; db < 4; ++db) oacc[hh][db] = fzero4();

  bf16x8 pf[2][2];
#pragma unroll
  for (int hh = 0; hh < 2; ++hh) {
    const int g = w + hh * 8;
    const int row = g * IT + lr;
    const int sw = row & 7;
    pf[hh][0] = *reinterpret_cast<const bf16x8*>(&sbP2[row * 64 + ((lg ^ sw) << 3)]);
    pf[hh][1] = *reinterpret_cast<const bf16x8*>(&sbP2[row * 64 + (((4 + lg) ^ sw) << 3)]);
  }
  auto pvdb = [&](bf16x8 (&buf)[2][2], int db) {
#pragma unroll
    for (int hh = 0; hh < 2; ++hh) {
      oacc[hh][db] = __builtin_amdgcn_mfma_f32_16x16x32_bf16(pf[hh][0], buf[hh][0], oacc[hh][db], 0, 0, 0);
      oacc[hh][db] = __builtin_amdgcn_mfma_f32_16x16x32_bf16(pf[hh][1], buf[hh][1], oacc[hh][db], 0, 0, 0);
    }
  };
  pvdb(vA, 0);  loadv(vA, 2);
  pvdb(vB, 1);  loadv(vB, 3);
  pvdb(vA, 2);
  pvdb(vB, 3);

  // epilogue: atomic partial-out
#pragma unroll
  for (int hh = 0; hh < 2; ++hh) {
    const int g = w + hh * 8;
    float* ob = Og + ((size_t)(b * NH + g) * NS + i0) * ND;
#pragma unroll
    for (int db = 0; db < 4; ++db)
#pragma unroll
      for (int rr = 0; rr < 4; ++rr)
        atomicAdd(&ob[(size_t)(lg * 4 + rr) * ND + db * 16 + lr], oacc[hh][db][rr]);
  }
}

extern "C" void kernel_launch(void* const* d_in, const int* in_sizes, int n_in,
                              void* d_out, int out_size, void* d_ws, size_t ws_size,
                              hipStream_t stream) {
  const float* Q     = (const float*)d_in[0];
  const float* K     = (const float*)d_in[1];
  const float* V     = (const float*)d_in[2];
  const float* BIAS  = (const float*)d_in[3];
  const float* WPRE  = (const float*)d_in[4];
  const float* WPOST = (const float*)d_in[5];
  float* OUT = (float*)d_out;
  (void)in_sizes; (void)n_in;

  const size_t nelem  = (size_t)NB * NH * NS * ND;              // 4.19M
  const size_t nbias  = (size_t)NH * NS * NS;                   // 16.8M
  const size_t lbytes = (size_t)NB * NH * NS * sizeof(float);   // 256KB
  const size_t need   = lbytes + (3 * nelem + nbias) * sizeof(__bf16);  // ~59MB

  float* Lws = (float*)d_ws;
  hipMemsetAsync(d_ws, 0, lbytes, stream);
  hipMemsetAsync(d_out, 0, (size_t)out_size * sizeof(float), stream);

  const int grid = NB * NITEM;  // 2176
  if (ws_size >= need) {
    __bf16* Qb = (__bf16*)((char*)d_ws + lbytes);
    __bf16* Kb = Qb + nelem;
    __bf16* VT = Kb + nelem;
    __bf16* BB = VT + nelem;
    hipLaunchKernelGGL(prep, dim3(QK_BLKS + VT_BLKS + BIAS_BLKS), dim3(256), 0, stream,
                       Q, K, V, BIAS, Qb, Kb, VT, BB);
    hipLaunchKernelGGL((attend_l<true>), dim3(grid), dim3(512), 0, stream,
                       Q, K, BIAS, WPRE, Qb, Kb, BB, Lws);
    hipLaunchKernelGGL((attend_o<true>), dim3(grid), dim3(512), 0, stream,
                       Q, K, V, BIAS, WPRE, WPOST, Qb, Kb, VT, BB, Lws, OUT);
  } else {
    hipLaunchKernelGGL((attend_l<false>), dim3(grid), dim3(512), 0, stream,
                       Q, K, BIAS, WPRE, (const __bf16*)nullptr,
                       (const __bf16*)nullptr, (const __bf16*)nullptr, Lws);
    hipLaunchKernelGGL((attend_o<false>), dim3(grid), dim3(512), 0, stream,
                       Q, K, V, BIAS, WPRE, WPOST, (const __bf16*)nullptr,
                       (const __bf16*)nullptr, (const __bf16*)nullptr,
                       (const __bf16*)nullptr, Lws, OUT);
  }
}

// Round 9
// 200.206 us; speedup vs baseline: 1.4257x; 1.2922x over previous
//
#include <hip/hip_runtime.h>
#include <math.h>

// Attend (talking-heads, causal) for B=4,H=16,N=1024,D=64 fp32.
// Round 9: kill the 35.6M output atomics (r8's wall). Kernel 1 (chunked,
// uniform WGs) stores unnormalized E[h,i,j] bf16 to ws + L atomic partials.
// Kernel 2 (1 WG per (b,row-tile), 16 waves = heads) folds 1/L into a
// per-i-scaled wpost fragment, streams E back coalesced, mix2 -> LDS -> PV,
// plain-stores its exclusive output tile. ws cascade: A(Qb/Kb/VT/E) ->
// B(VT/E) -> C(E) -> D(r8 fallback w/ atomics).

#define NB 4
#define NH 16
#define NS 1024
#define ND 64
#define IT 16
#define JT 64
#define NITEM 544
#define HPAD 24
#define PERB_E ((size_t)NITEM * 64 * 256)   // 8,912,896 elems per batch

typedef __bf16 bf16x8 __attribute__((ext_vector_type(8)));
typedef __bf16 bf16x4 __attribute__((ext_vector_type(4)));
typedef float  f32x4  __attribute__((ext_vector_type(4)));

__device__ __forceinline__ f32x4 fzero4() {
  f32x4 z; z[0] = 0.f; z[1] = 0.f; z[2] = 0.f; z[3] = 0.f; return z;
}

__device__ __forceinline__ void lgkm_barrier() {
  asm volatile("s_waitcnt lgkmcnt(0)" ::: "memory");
  __builtin_amdgcn_s_barrier();
}

// item q in [0,544) -> (i0, j0); r = 4m+t has m+1 chunks.
__device__ __forceinline__ void decode_item(int q, int& i0, int& j0) {
  int m = (int)sqrtf((float)q * 0.5f) + 1;
  while (2 * m * (m + 1) > q) --m;
  while (2 * (m + 1) * (m + 2) <= q) ++m;
  const int off = q - 2 * m * (m + 1);
  const int t = off / (m + 1);
  const int c = off - t * (m + 1);
  i0 = (4 * m + t) * IT;
  j0 = JT * c;
}

__device__ __forceinline__ size_t ebase64(int r) {   // 64-j units before row r
  const int m = r >> 2, t = r & 3;
  return (size_t)(r + 2 * m * (m - 1) + t * m);
}

// ---------------- prep kernels ----------------
#define QK_BLKS 8192
#define VT_BLKS 1024

__global__ __launch_bounds__(256)
void prep_qk(const float* __restrict__ Q, const float* __restrict__ K,
             __bf16* __restrict__ Qb, __bf16* __restrict__ Kb) {
  const size_t nq4 = (size_t)NB * NH * NS * ND / 4;
  size_t idx = (size_t)blockIdx.x * 256 + threadIdx.x;
  if (idx < nq4) {
    float4 x = reinterpret_cast<const float4*>(Q)[idx];
    bf16x4 o;
    o[0] = (__bf16)(x.x * 0.125f); o[1] = (__bf16)(x.y * 0.125f);
    o[2] = (__bf16)(x.z * 0.125f); o[3] = (__bf16)(x.w * 0.125f);
    reinterpret_cast<bf16x4*>(Qb)[idx] = o;
  } else {
    idx -= nq4;
    float4 x = reinterpret_cast<const float4*>(K)[idx];
    bf16x4 o;
    o[0] = (__bf16)x.x; o[1] = (__bf16)x.y; o[2] = (__bf16)x.z; o[3] = (__bf16)x.w;
    reinterpret_cast<bf16x4*>(Kb)[idx] = o;
  }
}

__global__ __launch_bounds__(256)
void prep_vt(const float* __restrict__ V, __bf16* __restrict__ VT) {
  __shared__ float tile[64][65];
  const int bh = blockIdx.x >> 4;
  const int j0 = (blockIdx.x & 15) * 64;
  const int t = threadIdx.x;
  const float* vp = V + ((size_t)bh * NS + j0) * ND;
#pragma unroll
  for (int rep = 0; rep < 4; ++rep) {
    int lin = rep * 256 + t;
    int jj = lin >> 4;
    int dd = (lin & 15) * 4;
    float4 x = *reinterpret_cast<const float4*>(vp + (size_t)jj * ND + dd);
    tile[jj][dd] = x.x; tile[jj][dd + 1] = x.y;
    tile[jj][dd + 2] = x.z; tile[jj][dd + 3] = x.w;
  }
  __syncthreads();
  __bf16* op = VT + (size_t)bh * ND * NS + j0;
#pragma unroll
  for (int rep = 0; rep < 16; ++rep) {
    int lin = rep * 256 + t;
    int d = lin >> 6;
    int jj = lin & 63;
    op[(size_t)d * NS + jj] = (__bf16)tile[jj][d];
  }
}

// ---------------- kernel 1: E + partial L (one chunk per WG) ----------------
template <bool QKWS>
__global__ __launch_bounds__(512, 4)
void attend_e(const float* __restrict__ Qg, const float* __restrict__ Kg,
              const float* __restrict__ Bg, const float* __restrict__ Wpre,
              const __bf16* __restrict__ Qb, const __bf16* __restrict__ Kb,
              __bf16* __restrict__ Ews, float* __restrict__ Lws)
{
  const int bid = blockIdx.x;
  const int b = bid / NITEM;
  int i0, jlo;
  decode_item(NITEM - 1 - (bid - b * NITEM), i0, jlo);
  const int r = i0 >> 4;
  __bf16* Eb = Ews + (size_t)b * PERB_E + ebase64(r) * 64 * 256;

  const int tid = threadIdx.x;
  const int w = tid >> 6;
  const int lane = tid & 63;
  const int lr = lane & 15;
  const int lg = lane >> 4;

  __shared__ __align__(16) __bf16 dots[IT * JT * HPAD];  // 48KB

  bf16x8 kreg[2][4][2];
#pragma unroll
  for (int hh = 0; hh < 2; ++hh) {
    const int h = w + hh * 8;
#pragma unroll
    for (int jb = 0; jb < 4; ++jb)
#pragma unroll
      for (int ks = 0; ks < 2; ++ks) {
        if constexpr (QKWS) {
          kreg[hh][jb][ks] = *reinterpret_cast<const bf16x8*>(
              Kb + ((size_t)(b * NH + h) * NS + jlo + jb * 16 + lr) * ND + ks * 32 + lg * 8);
        } else {
          const float* kp = Kg + ((size_t)(b * NH + h) * NS + jlo + jb * 16 + lr) * ND + ks * 32 + lg * 8;
          float4 x = *reinterpret_cast<const float4*>(kp);
          float4 y = *reinterpret_cast<const float4*>(kp + 4);
          bf16x8 f;
          f[0] = (__bf16)x.x; f[1] = (__bf16)x.y; f[2] = (__bf16)x.z; f[3] = (__bf16)x.w;
          f[4] = (__bf16)y.x; f[5] = (__bf16)y.y; f[6] = (__bf16)y.z; f[7] = (__bf16)y.w;
          kreg[hh][jb][ks] = f;
        }
      }
  }
  bf16x8 qF[2][2];
#pragma unroll
  for (int hh = 0; hh < 2; ++hh) {
    const int h = w + hh * 8;
    if constexpr (QKWS) {
      const __bf16* qp = Qb + ((size_t)(b * NH + h) * NS + i0 + lr) * ND + lg * 8;
      qF[hh][0] = *reinterpret_cast<const bf16x8*>(qp);
      qF[hh][1] = *reinterpret_cast<const bf16x8*>(qp + 32);
    } else {
      const float* qp = Qg + ((size_t)(b * NH + h) * NS + i0 + lr) * ND + lg * 8;
#pragma unroll
      for (int ks = 0; ks < 2; ++ks) {
        float4 x = *reinterpret_cast<const float4*>(qp + ks * 32);
        float4 y = *reinterpret_cast<const float4*>(qp + ks * 32 + 4);
        bf16x8 f;
        f[0] = (__bf16)(x.x * 0.125f); f[1] = (__bf16)(x.y * 0.125f);
        f[2] = (__bf16)(x.z * 0.125f); f[3] = (__bf16)(x.w * 0.125f);
        f[4] = (__bf16)(y.x * 0.125f); f[5] = (__bf16)(y.y * 0.125f);
        f[6] = (__bf16)(y.z * 0.125f); f[7] = (__bf16)(y.w * 0.125f);
        qF[hh][ks] = f;
      }
    }
  }
  bf16x8 wpreF;
#pragma unroll
  for (int e = 0; e < 8; ++e) wpreF[e] = (__bf16)0.f;
  if (lg < 2) {
#pragma unroll
    for (int e = 0; e < 8; ++e) wpreF[e] = (__bf16)Wpre[lr * NH + lg * 8 + e];
  }

  // phase1: QK -> dots
#pragma unroll
  for (int hh = 0; hh < 2; ++hh) {
    const int h = w + hh * 8;
#pragma unroll
    for (int jb = 0; jb < 4; ++jb) {
      f32x4 acc = fzero4();
#pragma unroll
      for (int ks = 0; ks < 2; ++ks)
        acc = __builtin_amdgcn_mfma_f32_16x16x32_bf16(qF[hh][ks], kreg[hh][jb][ks], acc, 0, 0, 0);
#pragma unroll
      for (int rr = 0; rr < 4; ++rr)
        dots[((lg * 4 + rr) * JT + jb * 16 + lr) * HPAD + h] = (__bf16)acc[rr];
    }
  }
  lgkm_barrier();

  // phase2: bias (fp32), mix1, exp -> L partials + E store
  float br[2][4][4];
#pragma unroll
  for (int ii = 0; ii < 2; ++ii) {
    const int gi = i0 + w + ii * 8;
#pragma unroll
    for (int qq = 0; qq < 4; ++qq)
#pragma unroll
      for (int rr = 0; rr < 4; ++rr)
        br[ii][qq][rr] = Bg[((size_t)(lg * 4 + rr) * NS + gi) * NS + jlo + qq * 16 + lr];
  }
  float Lp[2][4];
#pragma unroll
  for (int ii = 0; ii < 2; ++ii)
#pragma unroll
    for (int rr = 0; rr < 4; ++rr) Lp[ii][rr] = 0.f;

#pragma unroll
  for (int ii = 0; ii < 2; ++ii) {
    const int i = w + ii * 8;
    const int gi = i0 + i;
#pragma unroll
    for (int qq = 0; qq < 4; ++qq) {
      bf16x8 bfr;
#pragma unroll
      for (int e = 0; e < 8; ++e) bfr[e] = (__bf16)0.f;
      if (lg < 2)
        bfr = *reinterpret_cast<const bf16x8*>(&dots[(i * JT + qq * 16 + lr) * HPAD + lg * 8]);
      f32x4 s1 = __builtin_amdgcn_mfma_f32_16x16x32_bf16(wpreF, bfr, fzero4(), 0, 0, 0);
      const int gj = jlo + qq * 16 + lr;
      bf16x4 epack;
#pragma unroll
      for (int rr = 0; rr < 4; ++rr) {
        float ev = 0.f;
        if (gj <= gi) ev = __expf(s1[rr] + br[ii][qq][rr]);
        Lp[ii][rr] += ev;
        epack[rr] = (__bf16)ev;
      }
      *reinterpret_cast<bf16x4*>(Eb + (size_t)gj * 256 + i * 16 + lg * 4) = epack;
    }
  }

#pragma unroll
  for (int ii = 0; ii < 2; ++ii)
#pragma unroll
    for (int rr = 0; rr < 4; ++rr) {
      float v = Lp[ii][rr];
      v += __shfl_xor(v, 1, 64);
      v += __shfl_xor(v, 2, 64);
      v += __shfl_xor(v, 4, 64);
      v += __shfl_xor(v, 8, 64);
      if (lr == 0)
        atomicAdd(&Lws[(size_t)(b * NH + lg * 4 + rr) * NS + i0 + w + ii * 8], v);
    }
}

// ---------------- kernel 2: mix2 + PV, exclusive output tile ----------------
template <bool VWS>
__global__ __launch_bounds__(1024, 4)
void attend_pv(const float* __restrict__ Vg, const float* __restrict__ Wpost,
               const __bf16* __restrict__ VTb, const __bf16* __restrict__ Ews,
               const float* __restrict__ Lws, float* __restrict__ Og)
{
  const int bid = blockIdx.x;          // 0..255
  const int b = bid & 3;
  const int r = 63 - (bid >> 2);       // heavy rows first
  const int i0 = r * IT;
  const int nsteps = (r >> 2) + 1;
  const __bf16* Eb = Ews + (size_t)b * PERB_E + ebase64(r) * 64 * 256;

  const int tid = threadIdx.x;
  const int w = tid >> 6;              // wave = head g = mix2 row i
  const int lane = tid & 63;
  const int lr = lane & 15;
  const int lg = lane >> 4;

  __shared__ __align__(16) __bf16 sbP2[256 * 64];  // 32KB, XOR-swizzled

  // wpost scaled by 1/L[h][i0+w]  (exact fold of softmax normalization)
  bf16x8 wpostF;
#pragma unroll
  for (int e = 0; e < 8; ++e) wpostF[e] = (__bf16)0.f;
  if (lg < 2) {
#pragma unroll
    for (int e = 0; e < 8; ++e) {
      const int h = lg * 8 + e;
      const float L = Lws[(size_t)(b * NH + h) * NS + i0 + w];
      wpostF[e] = (__bf16)(Wpost[lr * NH + h] / L);
    }
  }

  f32x4 oacc[4];
#pragma unroll
  for (int db = 0; db < 4; ++db) oacc[db] = fzero4();

  bf16x8 eA[4], eB[4];
  auto load_e = [&](bf16x8 (&buf)[4], int j0) {
#pragma unroll
    for (int qq = 0; qq < 4; ++qq) {
#pragma unroll
      for (int e = 0; e < 8; ++e) buf[qq][e] = (__bf16)0.f;
      if (lg < 2)
        buf[qq] = *reinterpret_cast<const bf16x8*>(
            Eb + (size_t)(j0 + qq * 16 + lr) * 256 + w * 16 + lg * 8);
    }
  };

  auto do_step = [&](int s, bf16x8 (&ecur)[4], bf16x8 (&enxt)[4]) {
    const int j0 = s * JT;
    if (s) lgkm_barrier();             // prev PV LDS reads done
    // issue V(s)
    bf16x8 vf[4][2];
    if constexpr (VWS) {
#pragma unroll
      for (int db = 0; db < 4; ++db) {
        const __bf16* vp = VTb + ((size_t)(b * NH + w) * ND + db * 16 + lr) * NS + j0 + lg * 8;
        vf[db][0] = *reinterpret_cast<const bf16x8*>(vp);
        vf[db][1] = *reinterpret_cast<const bf16x8*>(vp + 32);
      }
    } else {
      const float* vb = Vg + (size_t)(b * NH + w) * NS * ND;
#pragma unroll
      for (int db = 0; db < 4; ++db) {
        bf16x8 f0, f1;
#pragma unroll
        for (int e = 0; e < 8; ++e) {
          f0[e] = (__bf16)vb[(size_t)(j0 + lg * 8 + e) * ND + db * 16 + lr];
          f1[e] = (__bf16)vb[(size_t)(j0 + 32 + lg * 8 + e) * ND + db * 16 + lr];
        }
        vf[db][0] = f0; vf[db][1] = f1;
      }
    }
    if (s + 1 < nsteps) load_e(enxt, j0 + JT);   // E prefetch (dbuf)
    // mix2: P2[g][i=w][j] for all g
#pragma unroll
    for (int qq = 0; qq < 4; ++qq) {
      f32x4 p2 = __builtin_amdgcn_mfma_f32_16x16x32_bf16(wpostF, ecur[qq], fzero4(), 0, 0, 0);
      const int u = (qq * 16 + lr) >> 3;
#pragma unroll
      for (int rr = 0; rr < 4; ++rr) {
        const int row = (lg * 4 + rr) * IT + w;
        sbP2[row * 64 + ((u ^ (w & 7)) << 3) + (lr & 7)] = (__bf16)p2[rr];
      }
    }
    lgkm_barrier();                    // P2 visible
    // PV head w
    const int row = w * IT + lr;
    const int sw = row & 7;
    bf16x8 pf0 = *reinterpret_cast<const bf16x8*>(&sbP2[row * 64 + ((lg ^ sw) << 3)]);
    bf16x8 pf1 = *reinterpret_cast<const bf16x8*>(&sbP2[row * 64 + (((4 + lg) ^ sw) << 3)]);
#pragma unroll
    for (int db = 0; db < 4; ++db) {
      oacc[db] = __builtin_amdgcn_mfma_f32_16x16x32_bf16(pf0, vf[db][0], oacc[db], 0, 0, 0);
      oacc[db] = __builtin_amdgcn_mfma_f32_16x16x32_bf16(pf1, vf[db][1], oacc[db], 0, 0, 0);
    }
  };

  load_e(eA, 0);
  for (int s = 0; s < nsteps; s += 2) {
    do_step(s, eA, eB);
    if (s + 1 < nsteps) do_step(s + 1, eB, eA);
  }

  // exclusive output tile: plain stores
  float* ob = Og + ((size_t)(b * NH + w) * NS + i0) * ND;
#pragma unroll
  for (int db = 0; db < 4; ++db)
#pragma unroll
    for (int rr = 0; rr < 4; ++rr)
      ob[(size_t)(lg * 4 + rr) * ND + db * 16 + lr] = oacc[db][rr];
}

// ---------------- fallback (path D): r8 kernels, fp32 direct ----------------
__global__ __launch_bounds__(512, 4)
void fb_attend_l(const float* __restrict__ Qg, const float* __restrict__ Kg,
                 const float* __restrict__ Bg, const float* __restrict__ Wpre,
                 float* __restrict__ Lws)
{
  const int bid = blockIdx.x;
  const int b = bid / NITEM;
  int i0, j0;
  decode_item(NITEM - 1 - (bid - b * NITEM), i0, j0);

  const int tid = threadIdx.x;
  const int w = tid >> 6;
  const int lane = tid & 63;
  const int lr = lane & 15;
  const int lg = lane >> 4;

  __shared__ __align__(16) __bf16 dots[IT * JT * HPAD];

  bf16x8 kreg[2][4][2];
#pragma unroll
  for (int hh = 0; hh < 2; ++hh) {
    const int h = w + hh * 8;
#pragma unroll
    for (int jb = 0; jb < 4; ++jb)
#pragma unroll
      for (int ks = 0; ks < 2; ++ks) {
        const float* kp = Kg + ((size_t)(b * NH + h) * NS + j0 + jb * 16 + lr) * ND + ks * 32 + lg * 8;
        float4 x = *reinterpret_cast<const float4*>(kp);
        float4 y = *reinterpret_cast<const float4*>(kp + 4);
        bf16x8 f;
        f[0] = (__bf16)x.x; f[1] = (__bf16)x.y; f[2] = (__bf16)x.z; f[3] = (__bf16)x.w;
        f[4] = (__bf16)y.x; f[5] = (__bf16)y.y; f[6] = (__bf16)y.z; f[7] = (__bf16)y.w;
        kreg[hh][jb][ks] = f;
      }
  }
  bf16x8 qF[2][2];
#pragma unroll
  for (int hh = 0; hh < 2; ++hh) {
    const int h = w + hh * 8;
    const float* qp = Qg + ((size_t)(b * NH + h) * NS + i0 + lr) * ND + lg * 8;
#pragma unroll
    for (int ks = 0; ks < 2; ++ks) {
      float4 x = *reinterpret_cast<const float4*>(qp + ks * 32);
      float4 y = *reinterpret_cast<const float4*>(qp + ks * 32 + 4);
      bf16x8 f;
      f[0] = (__bf16)(x.x * 0.125f); f[1] = (__bf16)(x.y * 0.125f);
      f[2] = (__bf16)(x.z * 0.125f); f[3] = (__bf16)(x.w * 0.125f);
      f[4] = (__bf16)(y.x * 0.125f); f[5] = (__bf16)(y.y * 0.125f);
      f[6] = (__bf16)(y.z * 0.125f); f[7] = (__bf16)(y.w * 0.125f);
      qF[hh][ks] = f;
    }
  }
  bf16x8 wpreF;
#pragma unroll
  for (int e = 0; e < 8; ++e) wpreF[e] = (__bf16)0.f;
  if (lg < 2) {
#pragma unroll
    for (int e = 0; e < 8; ++e) wpreF[e] = (__bf16)Wpre[lr * NH + lg * 8 + e];
  }

#pragma unroll
  for (int hh = 0; hh < 2; ++hh) {
    const int h = w + hh * 8;
#pragma unroll
    for (int jb = 0; jb < 4; ++jb) {
      f32x4 acc = fzero4();
#pragma unroll
      for (int ks = 0; ks < 2; ++ks)
        acc = __builtin_amdgcn_mfma_f32_16x16x32_bf16(qF[hh][ks], kreg[hh][jb][ks], acc, 0, 0, 0);
#pragma unroll
      for (int rr = 0; rr < 4; ++rr)
        dots[((lg * 4 + rr) * JT + jb * 16 + lr) * HPAD + h] = (__bf16)acc[rr];
    }
  }
  lgkm_barrier();

  float Lp[2][4];
#pragma unroll
  for (int ii = 0; ii < 2; ++ii)
#pragma unroll
    for (int rr = 0; rr < 4; ++rr) Lp[ii][rr] = 0.f;
#pragma unroll
  for (int ii = 0; ii < 2; ++ii) {
    const int i = w + ii * 8;
    const int gi = i0 + i;
#pragma unroll
    for (int qq = 0; qq < 4; ++qq) {
      bf16x8 bfr;
#pragma unroll
      for (int e = 0; e < 8; ++e) bfr[e] = (__bf16)0.f;
      if (lg < 2)
        bfr = *reinterpret_cast<const bf16x8*>(&dots[(i * JT + qq * 16 + lr) * HPAD + lg * 8]);
      f32x4 s1 = __builtin_amdgcn_mfma_f32_16x16x32_bf16(wpreF, bfr, fzero4(), 0, 0, 0);
      const int gj = j0 + qq * 16 + lr;
#pragma unroll
      for (int rr = 0; rr < 4; ++rr)
        if (gj <= gi)
          Lp[ii][rr] += __expf(s1[rr] + Bg[((size_t)(lg * 4 + rr) * NS + gi) * NS + gj]);
    }
  }
#pragma unroll
  for (int ii = 0; ii < 2; ++ii)
#pragma unroll
    for (int rr = 0; rr < 4; ++rr) {
      float v = Lp[ii][rr];
      v += __shfl_xor(v, 1, 64);
      v += __shfl_xor(v, 2, 64);
      v += __shfl_xor(v, 4, 64);
      v += __shfl_xor(v, 8, 64);
      if (lr == 0)
        atomicAdd(&Lws[(size_t)(b * NH + lg * 4 + rr) * NS + i0 + w + ii * 8], v);
    }
}

__global__ __launch_bounds__(512, 4)
void fb_attend_o(const float* __restrict__ Qg, const float* __restrict__ Kg,
                 const float* __restrict__ Vg, const float* __restrict__ Bg,
                 const float* __restrict__ Wpre, const float* __restrict__ Wpost,
                 const float* __restrict__ Lws, float* __restrict__ Og)
{
  const int bid = blockIdx.x;
  const int b = bid / NITEM;
  int i0, j0;
  decode_item(NITEM - 1 - (bid - b * NITEM), i0, j0);

  const int tid = threadIdx.x;
  const int w = tid >> 6;
  const int lane = tid & 63;
  const int lr = lane & 15;
  const int lg = lane >> 4;

  __shared__ __align__(16) __bf16 dots[IT * JT * HPAD];
  __shared__ __align__(16) __bf16 sbP2[256 * 64];

  bf16x8 kreg[2][4][2];
#pragma unroll
  for (int hh = 0; hh < 2; ++hh) {
    const int h = w + hh * 8;
#pragma unroll
    for (int jb = 0; jb < 4; ++jb)
#pragma unroll
      for (int ks = 0; ks < 2; ++ks) {
        const float* kp = Kg + ((size_t)(b * NH + h) * NS + j0 + jb * 16 + lr) * ND + ks * 32 + lg * 8;
        float4 x = *reinterpret_cast<const float4*>(kp);
        float4 y = *reinterpret_cast<const float4*>(kp + 4);
        bf16x8 f;
        f[0] = (__bf16)x.x; f[1] = (__bf16)x.y; f[2] = (__bf16)x.z; f[3] = (__bf16)x.w;
        f[4] = (__bf16)y.x; f[5] = (__bf16)y.y; f[6] = (__bf16)y.z; f[7] = (__bf16)y.w;
        kreg[hh][jb][ks] = f;
      }
  }
  bf16x8 qF[2][2];
#pragma unroll
  for (int hh = 0; hh < 2; ++hh) {
    const int h = w + hh * 8;
    const float* qp = Qg + ((size_t)(b * NH + h) * NS + i0 + lr) * ND + lg * 8;
#pragma unroll
    for (int ks = 0; ks < 2; ++ks) {
      float4 x = *reinterpret_cast<const float4*>(qp + ks * 32);
      float4 y = *reinterpret_cast<const float4*>(qp + ks * 32 + 4);
      bf16x8 f;
      f[0] = (__bf16)(x.x * 0.125f); f[1] = (__bf16)(x.y * 0.125f);
      f[2] = (__bf16)(x.z * 0.125f); f[3] = (__bf16)(x.w * 0.125f);
      f[4] = (__bf16)(y.x * 0.125f); f[5] = (__bf16)(y.y * 0.125f);
      f[6] = (__bf16)(y.z * 0.125f); f[7] = (__bf16)(y.w * 0.125f);
      qF[hh][ks] = f;
    }
  }
  bf16x8 wpreF, wpostF;
#pragma unroll
  for (int e = 0; e < 8; ++e) { wpreF[e] = (__bf16)0.f; wpostF[e] = (__bf16)0.f; }
  if (lg < 2) {
#pragma unroll
    for (int e = 0; e < 8; ++e) {
      wpreF[e]  = (__bf16)Wpre [lr * NH + lg * 8 + e];
      wpostF[e] = (__bf16)Wpost[lr * NH + lg * 8 + e];
    }
  }

#pragma unroll
  for (int hh = 0; hh < 2; ++hh) {
    const int h = w + hh * 8;
#pragma unroll
    for (int jb = 0; jb < 4; ++jb) {
      f32x4 acc = fzero4();
#pragma unroll
      for (int ks = 0; ks < 2; ++ks)
        acc = __builtin_amdgcn_mfma_f32_16x16x32_bf16(qF[hh][ks], kreg[hh][jb][ks], acc, 0, 0, 0);
#pragma unroll
      for (int rr = 0; rr < 4; ++rr)
        dots[((lg * 4 + rr) * JT + jb * 16 + lr) * HPAD + h] = (__bf16)acc[rr];
    }
  }
  lgkm_barrier();

  float linv[2][4];
#pragma unroll
  for (int ii = 0; ii < 2; ++ii)
#pragma unroll
    for (int rr = 0; rr < 4; ++rr)
      linv[ii][rr] = 1.f / Lws[(size_t)(b * NH + lg * 4 + rr) * NS + i0 + w + ii * 8];

#pragma unroll
  for (int ii = 0; ii < 2; ++ii) {
    const int i = w + ii * 8;
    const int gi = i0 + i;
#pragma unroll
    for (int qq = 0; qq < 4; ++qq) {
      bf16x8 bfr;
#pragma unroll
      for (int e = 0; e < 8; ++e) bfr[e] = (__bf16)0.f;
      if (lg < 2)
        bfr = *reinterpret_cast<const bf16x8*>(&dots[(i * JT + qq * 16 + lr) * HPAD + lg * 8]);
      f32x4 s1 = __builtin_amdgcn_mfma_f32_16x16x32_bf16(wpreF, bfr, fzero4(), 0, 0, 0);
      const int gj = j0 + qq * 16 + lr;
      const int cc = i * JT + qq * 16 + lr;
#pragma unroll
      for (int rr = 0; rr < 4; ++rr) {
        float ev = 0.f;
        if (gj <= gi)
          ev = __expf(s1[rr] + Bg[((size_t)(lg * 4 + rr) * NS + gi) * NS + gj]) * linv[ii][rr];
        dots[cc * HPAD + lg * 4 + rr] = (__bf16)ev;
      }
    }
#pragma unroll
    for (int qq = 0; qq < 4; ++qq) {
      bf16x8 efr;
#pragma unroll
      for (int e = 0; e < 8; ++e) efr[e] = (__bf16)0.f;
      if (lg < 2)
        efr = *reinterpret_cast<const bf16x8*>(&dots[(i * JT + qq * 16 + lr) * HPAD + lg * 8]);
      f32x4 p2 = __builtin_amdgcn_mfma_f32_16x16x32_bf16(wpostF, efr, fzero4(), 0, 0, 0);
      const int u = (qq * 16 + lr) >> 3;
#pragma unroll
      for (int rr = 0; rr < 4; ++rr) {
        const int row = (lg * 4 + rr) * IT + i;
        sbP2[row * 64 + ((u ^ (i & 7)) << 3) + (lr & 7)] = (__bf16)p2[rr];
      }
    }
  }
  lgkm_barrier();

  f32x4 oacc[2][4];
#pragma unroll
  for (int hh = 0; hh < 2; ++hh)
#pragma unroll
    for (int db = 0; db < 4; ++db) oacc[hh][db] = fzero4();
#pragma unroll
  for (int hh = 0; hh < 2; ++hh) {
    const int g = w + hh * 8;
    const int row = g * IT + lr;
    const int sw = row & 7;
    bf16x8 pf0 = *reinterpret_cast<const bf16x8*>(&sbP2[row * 64 + ((lg ^ sw) << 3)]);
    bf16x8 pf1 = *reinterpret_cast<const bf16x8*>(&sbP2[row * 64 + (((4 + lg) ^ sw) << 3)]);
    const float* vb = Vg + (size_t)(b * NH + g) * NS * ND;
#pragma unroll
    for (int db = 0; db < 4; ++db) {
      bf16x8 vf0, vf1;
#pragma unroll
      for (int e = 0; e < 8; ++e) {
        vf0[e] = (__bf16)vb[(size_t)(j0 + lg * 8 + e) * ND + db * 16 + lr];
        vf1[e] = (__bf16)vb[(size_t)(j0 + 32 + lg * 8 + e) * ND + db * 16 + lr];
      }
      oacc[hh][db] = __builtin_amdgcn_mfma_f32_16x16x32_bf16(pf0, vf0, oacc[hh][db], 0, 0, 0);
      oacc[hh][db] = __builtin_amdgcn_mfma_f32_16x16x32_bf16(pf1, vf1, oacc[hh][db], 0, 0, 0);
    }
  }
#pragma unroll
  for (int hh = 0; hh < 2; ++hh) {
    const int g = w + hh * 8;
    float* ob = Og + ((size_t)(b * NH + g) * NS + i0) * ND;
#pragma unroll
    for (int db = 0; db < 4; ++db)
#pragma unroll
      for (int rr = 0; rr < 4; ++rr)
        atomicAdd(&ob[(size_t)(lg * 4 + rr) * ND + db * 16 + lr], oacc[hh][db][rr]);
  }
}

extern "C" void kernel_launch(void* const* d_in, const int* in_sizes, int n_in,
                              void* d_out, int out_size, void* d_ws, size_t ws_size,
                              hipStream_t stream) {
  const float* Q     = (const float*)d_in[0];
  const float* K     = (const float*)d_in[1];
  const float* V     = (const float*)d_in[2];
  const float* BIAS  = (const float*)d_in[3];
  const float* WPRE  = (const float*)d_in[4];
  const float* WPOST = (const float*)d_in[5];
  float* OUT = (float*)d_out;
  (void)in_sizes; (void)n_in;

  const size_t nelem   = (size_t)NB * NH * NS * ND;        // 4,194,304
  const size_t E_BYTES = (size_t)NB * PERB_E * 2;          // 71,303,168
  const size_t off_E   = 1u << 20;                         // Lws in [0, 256KB)
  const size_t off_VT  = off_E + E_BYTES;
  const size_t off_Qb  = off_VT + nelem * 2;
  const size_t off_Kb  = off_Qb + nelem * 2;
  const size_t need_A  = off_Kb + nelem * 2;               // ~97.5 MB
  const size_t need_B  = off_Qb;                           // ~80.7 MB
  const size_t need_C  = off_VT;                           // ~72.4 MB

  float* Lws = (float*)d_ws;
  hipMemsetAsync(d_ws, 0, (size_t)NB * NH * NS * sizeof(float), stream);

  const int grid_e = NB * NITEM;   // 2176
  if (ws_size >= need_C) {
    __bf16* Ews = (__bf16*)((char*)d_ws + off_E);
    if (ws_size >= need_A) {
      __bf16* VT = (__bf16*)((char*)d_ws + off_VT);
      __bf16* Qb = (__bf16*)((char*)d_ws + off_Qb);
      __bf16* Kb = (__bf16*)((char*)d_ws + off_Kb);
      hipLaunchKernelGGL(prep_qk, dim3(QK_BLKS), dim3(256), 0, stream, Q, K, Qb, Kb);
      hipLaunchKernelGGL(prep_vt, dim3(VT_BLKS), dim3(256), 0, stream, V, VT);
      hipLaunchKernelGGL((attend_e<true>), dim3(grid_e), dim3(512), 0, stream,
                         Q, K, BIAS, WPRE, Qb, Kb, Ews, Lws);
      hipLaunchKernelGGL((attend_pv<true>), dim3(NB * 64), dim3(1024), 0, stream,
                         V, WPOST, VT, Ews, Lws, OUT);
    } else if (ws_size >= need_B) {
      __bf16* VT = (__bf16*)((char*)d_ws + off_VT);
      hipLaunchKernelGGL(prep_vt, dim3(VT_BLKS), dim3(256), 0, stream, V, VT);
      hipLaunchKernelGGL((attend_e<false>), dim3(grid_e), dim3(512), 0, stream,
                         Q, K, BIAS, WPRE, (const __bf16*)nullptr, (const __bf16*)nullptr,
                         Ews, Lws);
      hipLaunchKernelGGL((attend_pv<true>), dim3(NB * 64), dim3(1024), 0, stream,
                         V, WPOST, VT, Ews, Lws, OUT);
    } else {
      hipLaunchKernelGGL((attend_e<false>), dim3(grid_e), dim3(512), 0, stream,
                         Q, K, BIAS, WPRE, (const __bf16*)nullptr, (const __bf16*)nullptr,
                         Ews, Lws);
      hipLaunchKernelGGL((attend_pv<false>), dim3(NB * 64), dim3(1024), 0, stream,
                         V, WPOST, (const __bf16*)nullptr, Ews, Lws, OUT);
    }
  } else {
    hipMemsetAsync(d_out, 0, (size_t)out_size * sizeof(float), stream);
    hipLaunchKernelGGL(fb_attend_l, dim3(grid_e), dim3(512), 0, stream,
                       Q, K, BIAS, WPRE, Lws);
    hipLaunchKernelGGL(fb_attend_o, dim3(grid_e), dim3(512), 0, stream,
                       Q, K, V, BIAS, WPRE, WPOST, Lws, OUT);
  }
}